// Round 11
// baseline (145.529 us; speedup 1.0000x reference)
//
#include <hip/hip_runtime.h>
#include <cmath>

// Problem constants (Head: B=4, T=4096, N_EMBD=32, HEAD_SIZE=32)
#define BB 4
#define TT 4096
#define NE 32
#define HS 32

// R9 geometry kept: 512-key splits (best measured: 105.7).
#define IPB 576       // items per batch = sum_{tt=0}^{127} ceil((tt+1)/16)
#define MAXSP 8       // 512-key splits per 16-query slot (combiner view)
#define SLOT 288      // dwords per slot: [16 unused], l[16], O[16q][4 quad][4 dw]
#define FNEG (-1.0e30f)
#define BIAS 6.0f     // fixed softmax exponent bias (folded into QK mfma C)
#define SC2  0.25506953149031156f  // 32^-0.5 * log2(e), folded into Qh

// R11 DIAGNOSTIC: repeat the partial body 3x so the dispatch (~64 us)
// surfaces above the 42 us fill cutoff in top-5 WITH honest counters.
// Idempotent (pure function of inputs). This round's dur_us is knowingly
// sacrificed (~+43 us) to decide VALU-bound vs latency-bound.
#define REP 3

typedef unsigned int uint32;
typedef __fp16 half2v __attribute__((ext_vector_type(2)));
typedef __fp16 half4v __attribute__((ext_vector_type(4)));
typedef __fp16 half8v __attribute__((ext_vector_type(8)));
typedef float f32x4 __attribute__((ext_vector_type(4)));

__device__ __forceinline__ half2v u2h(uint32 u) {
    union { uint32 u; half2v h; } x; x.u = u; return x.h;
}

#if __has_builtin(__builtin_amdgcn_cvt_pkrtz)
__device__ __forceinline__ half2v pkf16(float a, float b) {
    return __builtin_amdgcn_cvt_pkrtz(a, b);
}
#else
__device__ __forceinline__ half2v pkf16(float a, float b) {
    half2v h; h.x = (__fp16)a; h.y = (__fp16)b; return h;
}
#endif

// ---------------------------------------------------------------------------
// Kernel 1: Q/K/V projection (fp32 math), f16 stores. R7 WIN kept: LDS-
// transposed weight staging (coalesced global reads, conflict-free LDS).
// ---------------------------------------------------------------------------
__global__ __launch_bounds__(256) void qkv_proj(
    const float* __restrict__ x,
    const float* __restrict__ Wq,
    const float* __restrict__ Wk,
    const float* __restrict__ Wv,
    __fp16* __restrict__ Qh, __fp16* __restrict__ Kh,
    __fp16* __restrict__ Vt8)
{
    __shared__ float Wt[3][NE][HS];   // Wt[m][d][h] = Wm[h*NE+d], 12 KB
    #pragma unroll
    for (int i = threadIdx.x; i < 3 * NE * HS; i += 256) {
        int m   = i >> 10;            // matrix 0..2
        int idx = i & 1023;           // contiguous within matrix
        int h   = idx >> 5;           // W row
        int d   = idx & 31;           // W col (contiguous across threads)
        const float* Wm = (m == 0) ? Wq : (m == 1) ? Wk : Wv;
        Wt[m][d][h] = Wm[h * NE + d];
    }
    __syncthreads();

    int tid = blockIdx.x * 256 + threadIdx.x;
    int row = tid >> 5;      // 0..16383  (b*T + t)
    int h   = tid & 31;
    const float4* xr4 = reinterpret_cast<const float4*>(x + (size_t)row * NE);
    float4 xv4[8];
    #pragma unroll
    for (int k = 0; k < 8; ++k) xv4[k] = xr4[k];
    const float* xv = (const float*)xv4;
    float aq = 0.f, ak = 0.f, av = 0.f;
    #pragma unroll
    for (int d = 0; d < NE; ++d) {
        aq = fmaf(xv[d], Wt[0][d][h], aq);
        ak = fmaf(xv[d], Wt[1][d][h], ak);
        av = fmaf(xv[d], Wt[2][d][h], av);
    }
    size_t o = (size_t)row * HS + h;
    Qh[o] = (__fp16)(aq * SC2);
    Kh[o] = (__fp16)ak;
    int b = row >> 12, t = row & (TT - 1);
    Vt8[((size_t)(b * (TT / 4) + (t >> 2)) * 16 + (h & 15)) * 8
        + (h >> 4) * 4 + (t & 3)] = (__fp16)av;
}

// ---------------------------------------------------------------------------
// Kernel 2: MFMA flash partials, 32-query tiles, 512-KEY SPLITS (R9 form),
// body repeated REP times (R11 diagnostic — see #define REP note).
// ---------------------------------------------------------------------------
__global__ __launch_bounds__(256, 4) void attn_partial(
    const __fp16* __restrict__ Qh, const __fp16* __restrict__ Kh,
    const __fp16* __restrict__ Vt8, float* __restrict__ part)
{
    int wave = threadIdx.x >> 6;
    int lane = threadIdx.x & 63;

    for (int rep = 0; rep < REP; ++rep) {
    asm volatile("" ::: "memory");   // keep reps distinct, no cross-rep CSE

    int item = (BB * IPB - 1) - (blockIdx.x * 4 + wave);   // LPT: heavy first
    int b = item / IPB;
    int r = item - b * IPB;
    // group g: prefix = 8g(g+1); solve 8g(g+1) <= r < 8(g+1)(g+2)
    int g = (int)((sqrtf((float)(4 + 2 * r)) - 2.0f) * 0.25f);
    if (g < 0) g = 0;
    while (8 * (g + 1) * (g + 2) <= r) ++g;
    while (8 * g * (g + 1) > r) --g;
    int rr = r - 8 * g * (g + 1);
    int tq = rr / (g + 1);           // 0..15
    int tt = 16 * g + tq;            // 32-query tile index, 0..127
    int sp = rr - tq * (g + 1);      // split index, 0..g
    int qt0 = tt * 32;
    int kbase = sp * 512;
    int kend  = min(kbase + 512, qt0 + 32);
    int nsub  = (kend - kbase) >> 4;      // even: 2..32
    bool hasdiag = (kend == qt0 + 32);    // true iff last split
    int nfast = nsub - (hasdiag ? 2 : 0);

    int c = lane & 15;   // query column (within each 16q fragment)
    int q = lane >> 4;   // quad

    const __fp16* Qb = Qh  + (size_t)b * TT * HS;
    const __fp16* Kb = Kh  + (size_t)b * TT * HS;
    const __fp16* Vb = Vt8 + (size_t)b * (TT / 4) * 128;

    union U4H8  { uint4 u; half8v h; };
    union U4H44 { uint4 u; half4v h4[2]; };
    union H4    { half4v h4; half2v h2[2]; };
    union H4U4  { half2v h[4]; uint4 u; };

    U4H8 qf0; qf0.u = *(const uint4*)(Qb + (size_t)(qt0 + c) * HS + 8 * q);
    U4H8 qf1; qf1.u = *(const uint4*)(Qb + (size_t)(qt0 + 16 + c) * HS + 8 * q);

    const f32x4 cbias = {-BIAS, -BIAS, -BIAS, -BIAS};
    float l0 = 0.f, l1 = 0.f;
    f32x4 o00 = {0.f,0.f,0.f,0.f}, o01 = o00, o10 = o00, o11 = o00;

    // ---- compute one 16-key subtile from preloaded fragments, no mask ----
    auto dofast = [&](U4H8 kf, U4H44 vf) {
        f32x4 s0 = __builtin_amdgcn_mfma_f32_16x16x32_f16(kf.h, qf0.h, cbias, 0, 0, 0);
        f32x4 s1 = __builtin_amdgcn_mfma_f32_16x16x32_f16(kf.h, qf1.h, cbias, 0, 0, 0);
        float p0[4], p1[4];
        #pragma unroll
        for (int j = 0; j < 4; ++j) {
            p0[j] = exp2f((s0[j] != -BIAS) ? s0[j] : FNEG);   // tril==0 quirk
            p1[j] = exp2f((s1[j] != -BIAS) ? s1[j] : FNEG);
        }
        l0 += (p0[0] + p0[1]) + (p0[2] + p0[3]);
        l1 += (p1[0] + p1[1]) + (p1[2] + p1[3]);
        H4 pf0; pf0.h2[0] = pkf16(p0[0], p0[1]); pf0.h2[1] = pkf16(p0[2], p0[3]);
        H4 pf1; pf1.h2[0] = pkf16(p1[0], p1[1]); pf1.h2[1] = pkf16(p1[2], p1[3]);
        o00 = __builtin_amdgcn_mfma_f32_16x16x16f16(vf.h4[0], pf0.h4, o00, 0, 0, 0);
        o01 = __builtin_amdgcn_mfma_f32_16x16x16f16(vf.h4[1], pf0.h4, o01, 0, 0, 0);
        o10 = __builtin_amdgcn_mfma_f32_16x16x16f16(vf.h4[0], pf1.h4, o10, 0, 0, 0);
        o11 = __builtin_amdgcn_mfma_f32_16x16x16f16(vf.h4[1], pf1.h4, o11, 0, 0, 0);
    };

    // ---- diagonal subtile: adds causal masks for both fragments ----
    auto domask = [&](int kb) {
        U4H8 kf; kf.u = *(const uint4*)(Kb + (size_t)(kb + c) * HS + 8 * q);
        U4H44 vf; vf.u = *(const uint4*)(Vb + (size_t)((kb >> 2) + q) * 128 + c * 8);
        f32x4 s0 = __builtin_amdgcn_mfma_f32_16x16x32_f16(kf.h, qf0.h, cbias, 0, 0, 0);
        f32x4 s1 = __builtin_amdgcn_mfma_f32_16x16x32_f16(kf.h, qf1.h, cbias, 0, 0, 0);
        int r0 = kb - qt0 + 4 * q;        // key offset rel. frag0 queries
        int r1 = r0 - 16;                 // rel. frag1 queries
        float p0[4], p1[4];
        #pragma unroll
        for (int j = 0; j < 4; ++j) {
            float w0 = (s0[j] != -BIAS) ? s0[j] : FNEG;
            float w1 = (s1[j] != -BIAS) ? s1[j] : FNEG;
            if (r0 + j > c) w0 = FNEG;    // causal (frag0)
            if (r1 + j > c) w1 = FNEG;    // causal (frag1)
            p0[j] = exp2f(w0);
            p1[j] = exp2f(w1);
        }
        l0 += (p0[0] + p0[1]) + (p0[2] + p0[3]);
        l1 += (p1[0] + p1[1]) + (p1[2] + p1[3]);
        H4 pf0; pf0.h2[0] = pkf16(p0[0], p0[1]); pf0.h2[1] = pkf16(p0[2], p0[3]);
        H4 pf1; pf1.h2[0] = pkf16(p1[0], p1[1]); pf1.h2[1] = pkf16(p1[2], p1[3]);
        o00 = __builtin_amdgcn_mfma_f32_16x16x16f16(vf.h4[0], pf0.h4, o00, 0, 0, 0);
        o01 = __builtin_amdgcn_mfma_f32_16x16x16f16(vf.h4[1], pf0.h4, o01, 0, 0, 0);
        o10 = __builtin_amdgcn_mfma_f32_16x16x16f16(vf.h4[0], pf1.h4, o10, 0, 0, 0);
        o11 = __builtin_amdgcn_mfma_f32_16x16x16f16(vf.h4[1], pf1.h4, o11, 0, 0, 0);
    };

    // ---- software-pipelined fast loop: prefetch i+1 while computing i ----
    int kb = kbase;
    U4H8  kf; kf.u = *(const uint4*)(Kb + (size_t)(kb + c) * HS + 8 * q);
    U4H44 vf; vf.u = *(const uint4*)(Vb + (size_t)((kb >> 2) + q) * 128 + c * 8);
    #pragma unroll 2
    for (int i = 0; i < nfast; ++i) {
        int kb2 = kb + 16;
        // Prefetch: in-bounds for every split (kb2+16 <= kend <= T).
        U4H8  kf2; kf2.u = *(const uint4*)(Kb + (size_t)(kb2 + c) * HS + 8 * q);
        U4H44 vf2; vf2.u = *(const uint4*)(Vb + (size_t)((kb2 >> 2) + q) * 128 + c * 8);
        dofast(kf, vf);
        kf = kf2; vf = vf2; kb = kb2;
    }
    if (hasdiag) { domask(kb); domask(kb + 16); }

    // l: sum over quads (each lane's l covers its quad's keys)
    float lt0 = l0 + __shfl_xor(l0, 16); lt0 += __shfl_xor(lt0, 32);
    float lt1 = l1 + __shfl_xor(l1, 16); lt1 += __shfl_xor(lt1, 32);

    // two 16-query slots: t16 = 2tt (frag0), 2tt+1 (frag1), same sp
    float* P0 = part + (size_t)((b * 256 + 2 * tt) * MAXSP + sp) * SLOT;
    float* P1 = P0 + (size_t)MAXSP * SLOT;
    if (q == 0) { P0[16 + c] = lt0; P1[16 + c] = lt1; }
    // O region: [query c][quad q][4 dwords] — one uint4 store per lane/frag
    H4U4 a;
    a.h[0] = pkf16(o00[0], o00[1]); a.h[1] = pkf16(o00[2], o00[3]);
    a.h[2] = pkf16(o01[0], o01[1]); a.h[3] = pkf16(o01[2], o01[3]);
    *((uint4*)((uint32*)(P0 + 32) + c * 16 + q * 4)) = a.u;
    a.h[0] = pkf16(o10[0], o10[1]); a.h[1] = pkf16(o10[2], o10[3]);
    a.h[2] = pkf16(o11[0], o11[1]); a.h[3] = pkf16(o11[2], o11[3]);
    *((uint4*)((uint32*)(P1 + 32) + c * 16 + q * 4)) = a.u;

    }  // rep
}

// ---------------------------------------------------------------------------
// Kernel 3: combine splits (plain sums — shared fixed bias), normalize,
// write fp32 out. One thread per (b, 16q tile, query, quad): 65536 threads.
// ---------------------------------------------------------------------------
__global__ __launch_bounds__(256) void attn_combine(
    const float* __restrict__ part, float* __restrict__ out)
{
    int tid = blockIdx.x * 256 + threadIdx.x;  // 0..65535
    int hq = tid & 3;            // quad block: dims {4hq..4hq+3, 16+4hq..+3}
    int c  = (tid >> 2) & 15;
    int t  = (tid >> 6) & 255;
    int b  = tid >> 14;
    int ns = (t >> 5) + 1;       // 512-key splits covering this 16q tile

    const float* base = part + (size_t)(b * 256 + t) * MAXSP * SLOT;

    float acc[8];
    #pragma unroll
    for (int k = 0; k < 8; ++k) acc[k] = 0.f;
    float L = 0.f;
    for (int s = 0; s < ns; ++s) {
        const float* P = base + (size_t)s * SLOT;
        L += P[16 + c];
        uint4 ov = *(const uint4*)((const uint32*)(P + 32) + c * 16 + 4 * hq);
        const uint32* ovp = (const uint32*)&ov;
        #pragma unroll
        for (int pr = 0; pr < 4; ++pr) {
            half2v hh = u2h(ovp[pr]);
            acc[2 * pr]     += (float)hh.x;
            acc[2 * pr + 1] += (float)hh.y;
        }
    }
    float invL = 1.0f / L;
    float* orow = out + ((size_t)(b * TT + t * 16 + c)) * HS;
    float4 w0 = {acc[0] * invL, acc[1] * invL, acc[2] * invL, acc[3] * invL};
    float4 w1 = {acc[4] * invL, acc[5] * invL, acc[6] * invL, acc[7] * invL};
    *(float4*)(orow + 4 * hq) = w0;        // dims 4hq..4hq+3
    *(float4*)(orow + 16 + 4 * hq) = w1;   // dims 16+4hq..16+4hq+3
}

// ---------------------------------------------------------------------------
extern "C" void kernel_launch(void* const* d_in, const int* in_sizes, int n_in,
                              void* d_out, int out_size, void* d_ws, size_t ws_size,
                              hipStream_t stream)
{
    const float* x  = (const float*)d_in[0];
    const float* Wq = (const float*)d_in[1];
    const float* Wk = (const float*)d_in[2];
    const float* Wv = (const float*)d_in[3];
    float* out = (float*)d_out;

    __fp16* Qh  = (__fp16*)d_ws;                        // 1 MB
    __fp16* Kh  = Qh + (size_t)BB * TT * HS;            // 1 MB
    __fp16* Vt8 = Kh + (size_t)BB * TT * HS;            // 1 MB
    float* part = (float*)(Vt8 + (size_t)BB * TT * HS); // 8192 slots * 1152 B

    qkv_proj<<<dim3((BB * TT * HS) / 256), dim3(256), 0, stream>>>(
        x, Wq, Wk, Wv, Qh, Kh, Vt8);
    attn_partial<<<dim3((BB * IPB) / 4), dim3(256), 0, stream>>>(
        Qh, Kh, Vt8, part);
    attn_combine<<<dim3(256), dim3(256), 0, stream>>>(part, out);
}

// Round 12
// 105.937 us; speedup vs baseline: 1.3737x; 1.3737x over previous
//
#include <hip/hip_runtime.h>
#include <cmath>

// Problem constants (Head: B=4, T=4096, N_EMBD=32, HEAD_SIZE=32)
#define BB 4
#define TT 4096
#define NE 32
#define HS 32

// R9 geometry kept: 512-key splits (best measured: 105.7).
#define IPB 576       // items per batch = sum_{tt=0}^{127} ceil((tt+1)/16)
#define MAXSP 8       // 512-key splits per 16-query slot (combiner view)
#define SLOT 288      // dwords per slot: [16 unused], l[16], O[16q][4 quad][4 dw]
#define FNEG (-1.0e30f)
#define BIAS 6.0f     // fixed softmax exponent bias (folded into QK mfma C)
#define SC2  0.25506953149031156f  // 32^-0.5 * log2(e), folded into Qh

typedef unsigned int uint32;
typedef __fp16 half2v __attribute__((ext_vector_type(2)));
typedef __fp16 half4v __attribute__((ext_vector_type(4)));
typedef __fp16 half8v __attribute__((ext_vector_type(8)));
typedef float f32x4 __attribute__((ext_vector_type(4)));

__device__ __forceinline__ half2v u2h(uint32 u) {
    union { uint32 u; half2v h; } x; x.u = u; return x.h;
}

#if __has_builtin(__builtin_amdgcn_cvt_pkrtz)
__device__ __forceinline__ half2v pkf16(float a, float b) {
    return __builtin_amdgcn_cvt_pkrtz(a, b);
}
#else
__device__ __forceinline__ half2v pkf16(float a, float b) {
    half2v h; h.x = (__fp16)a; h.y = (__fp16)b; return h;
}
#endif

// ---------------------------------------------------------------------------
// Kernel 1: Q/K/V projection (fp32 math), f16 stores. R7 WIN kept: LDS-
// transposed weight staging (coalesced global reads, conflict-free LDS).
// ---------------------------------------------------------------------------
__global__ __launch_bounds__(256) void qkv_proj(
    const float* __restrict__ x,
    const float* __restrict__ Wq,
    const float* __restrict__ Wk,
    const float* __restrict__ Wv,
    __fp16* __restrict__ Qh, __fp16* __restrict__ Kh,
    __fp16* __restrict__ Vt8)
{
    __shared__ float Wt[3][NE][HS];   // Wt[m][d][h] = Wm[h*NE+d], 12 KB
    #pragma unroll
    for (int i = threadIdx.x; i < 3 * NE * HS; i += 256) {
        int m   = i >> 10;            // matrix 0..2
        int idx = i & 1023;           // contiguous within matrix
        int h   = idx >> 5;           // W row
        int d   = idx & 31;           // W col (contiguous across threads)
        const float* Wm = (m == 0) ? Wq : (m == 1) ? Wk : Wv;
        Wt[m][d][h] = Wm[h * NE + d];
    }
    __syncthreads();

    int tid = blockIdx.x * 256 + threadIdx.x;
    int row = tid >> 5;      // 0..16383  (b*T + t)
    int h   = tid & 31;
    const float4* xr4 = reinterpret_cast<const float4*>(x + (size_t)row * NE);
    float4 xv4[8];
    #pragma unroll
    for (int k = 0; k < 8; ++k) xv4[k] = xr4[k];
    const float* xv = (const float*)xv4;
    float aq = 0.f, ak = 0.f, av = 0.f;
    #pragma unroll
    for (int d = 0; d < NE; ++d) {
        aq = fmaf(xv[d], Wt[0][d][h], aq);
        ak = fmaf(xv[d], Wt[1][d][h], ak);
        av = fmaf(xv[d], Wt[2][d][h], av);
    }
    size_t o = (size_t)row * HS + h;
    Qh[o] = (__fp16)(aq * SC2);
    Kh[o] = (__fp16)ak;
    int b = row >> 12, t = row & (TT - 1);
    Vt8[((size_t)(b * (TT / 4) + (t >> 2)) * 16 + (h & 15)) * 8
        + (h >> 4) * 4 + (t & 3)] = (__fp16)av;
}

// ---------------------------------------------------------------------------
// Kernel 2: MFMA flash partials, 32-query tiles, 512-KEY SPLITS.
// R12 (from R11's honest counters: VALU ~17%/SIMD, MFMA 10%, latency-bound):
//  * 2-DEEP K/V prefetch — loads issued 2 subtiles ahead (~300 cy covered);
//    diagonal fragments arrive pre-loaded (domask loads deleted).
//  * l accumulated via MFMA (ones-A x P = column sums): deletes 8 VALU adds
//    per subtile + the epilogue shfl_xor chain; matrix pipe was 10% busy.
//  * unroll 4 to amortize addressing VALU.
// Bounds: prefetch max row < kend+32 <= qt0+32 <= TT for every split — always
// inside this batch's K/V region.
// ---------------------------------------------------------------------------
__global__ __launch_bounds__(256, 4) void attn_partial(
    const __fp16* __restrict__ Qh, const __fp16* __restrict__ Kh,
    const __fp16* __restrict__ Vt8, float* __restrict__ part)
{
    int wave = threadIdx.x >> 6;
    int lane = threadIdx.x & 63;
    int item = (BB * IPB - 1) - (blockIdx.x * 4 + wave);   // LPT: heavy first
    int b = item / IPB;
    int r = item - b * IPB;
    // group g: prefix = 8g(g+1); solve 8g(g+1) <= r < 8(g+1)(g+2)
    int g = (int)((sqrtf((float)(4 + 2 * r)) - 2.0f) * 0.25f);
    if (g < 0) g = 0;
    while (8 * (g + 1) * (g + 2) <= r) ++g;
    while (8 * g * (g + 1) > r) --g;
    int rr = r - 8 * g * (g + 1);
    int tq = rr / (g + 1);           // 0..15
    int tt = 16 * g + tq;            // 32-query tile index, 0..127
    int sp = rr - tq * (g + 1);      // split index, 0..g
    int qt0 = tt * 32;
    int kbase = sp * 512;
    int kend  = min(kbase + 512, qt0 + 32);
    int nsub  = (kend - kbase) >> 4;      // even: 2..32
    bool hasdiag = (kend == qt0 + 32);    // true iff last split
    int nfast = nsub - (hasdiag ? 2 : 0);

    int c = lane & 15;   // query column (within each 16q fragment)
    int q = lane >> 4;   // quad

    const __fp16* Qb = Qh  + (size_t)b * TT * HS;
    const __fp16* Kb = Kh  + (size_t)b * TT * HS;
    const __fp16* Vb = Vt8 + (size_t)b * (TT / 4) * 128;

    union U4H8  { uint4 u; half8v h; };
    union U4H44 { uint4 u; half4v h4[2]; };
    union H4    { half4v h4; half2v h2[2]; };
    union H4U4  { half2v h[4]; uint4 u; };

    U4H8 qf0; qf0.u = *(const uint4*)(Qb + (size_t)(qt0 + c) * HS + 8 * q);
    U4H8 qf1; qf1.u = *(const uint4*)(Qb + (size_t)(qt0 + 16 + c) * HS + 8 * q);

    const f32x4 cbias = {-BIAS, -BIAS, -BIAS, -BIAS};
    const half4v vones = {(__fp16)1.0f, (__fp16)1.0f, (__fp16)1.0f, (__fp16)1.0f};
    f32x4 o00 = {0.f,0.f,0.f,0.f}, o01 = o00, o10 = o00, o11 = o00;
    f32x4 al0 = o00, al1 = o00;      // l accumulators (ones-A MFMA)

    // ---- one 16-key subtile from preloaded fragments, no causal mask ----
    auto dofast = [&](U4H8 kf, U4H44 vf) {
        f32x4 s0 = __builtin_amdgcn_mfma_f32_16x16x32_f16(kf.h, qf0.h, cbias, 0, 0, 0);
        f32x4 s1 = __builtin_amdgcn_mfma_f32_16x16x32_f16(kf.h, qf1.h, cbias, 0, 0, 0);
        float p0[4], p1[4];
        #pragma unroll
        for (int j = 0; j < 4; ++j) {
            p0[j] = exp2f((s0[j] != -BIAS) ? s0[j] : FNEG);   // tril==0 quirk
            p1[j] = exp2f((s1[j] != -BIAS) ? s1[j] : FNEG);
        }
        H4 pf0; pf0.h2[0] = pkf16(p0[0], p0[1]); pf0.h2[1] = pkf16(p0[2], p0[3]);
        H4 pf1; pf1.h2[0] = pkf16(p1[0], p1[1]); pf1.h2[1] = pkf16(p1[2], p1[3]);
        al0 = __builtin_amdgcn_mfma_f32_16x16x16f16(vones,     pf0.h4, al0, 0, 0, 0);
        al1 = __builtin_amdgcn_mfma_f32_16x16x16f16(vones,     pf1.h4, al1, 0, 0, 0);
        o00 = __builtin_amdgcn_mfma_f32_16x16x16f16(vf.h4[0], pf0.h4, o00, 0, 0, 0);
        o01 = __builtin_amdgcn_mfma_f32_16x16x16f16(vf.h4[1], pf0.h4, o01, 0, 0, 0);
        o10 = __builtin_amdgcn_mfma_f32_16x16x16f16(vf.h4[0], pf1.h4, o10, 0, 0, 0);
        o11 = __builtin_amdgcn_mfma_f32_16x16x16f16(vf.h4[1], pf1.h4, o11, 0, 0, 0);
    };

    // ---- diagonal subtile (preloaded fragments): adds causal masks ----
    auto domask = [&](U4H8 kf, U4H44 vf, int kb) {
        f32x4 s0 = __builtin_amdgcn_mfma_f32_16x16x32_f16(kf.h, qf0.h, cbias, 0, 0, 0);
        f32x4 s1 = __builtin_amdgcn_mfma_f32_16x16x32_f16(kf.h, qf1.h, cbias, 0, 0, 0);
        int r0 = kb - qt0 + 4 * q;        // key offset rel. frag0 queries
        int r1 = r0 - 16;                 // rel. frag1 queries
        float p0[4], p1[4];
        #pragma unroll
        for (int j = 0; j < 4; ++j) {
            float w0 = (s0[j] != -BIAS) ? s0[j] : FNEG;
            float w1 = (s1[j] != -BIAS) ? s1[j] : FNEG;
            if (r0 + j > c) w0 = FNEG;    // causal (frag0)
            if (r1 + j > c) w1 = FNEG;    // causal (frag1)
            p0[j] = exp2f(w0);
            p1[j] = exp2f(w1);
        }
        H4 pf0; pf0.h2[0] = pkf16(p0[0], p0[1]); pf0.h2[1] = pkf16(p0[2], p0[3]);
        H4 pf1; pf1.h2[0] = pkf16(p1[0], p1[1]); pf1.h2[1] = pkf16(p1[2], p1[3]);
        al0 = __builtin_amdgcn_mfma_f32_16x16x16f16(vones,     pf0.h4, al0, 0, 0, 0);
        al1 = __builtin_amdgcn_mfma_f32_16x16x16f16(vones,     pf1.h4, al1, 0, 0, 0);
        o00 = __builtin_amdgcn_mfma_f32_16x16x16f16(vf.h4[0], pf0.h4, o00, 0, 0, 0);
        o01 = __builtin_amdgcn_mfma_f32_16x16x16f16(vf.h4[1], pf0.h4, o01, 0, 0, 0);
        o10 = __builtin_amdgcn_mfma_f32_16x16x16f16(vf.h4[0], pf1.h4, o10, 0, 0, 0);
        o11 = __builtin_amdgcn_mfma_f32_16x16x16f16(vf.h4[1], pf1.h4, o11, 0, 0, 0);
    };

    // ---- 2-deep software-pipelined fast loop ----
    int kb = kbase;
    U4H8  kfa, kfb; U4H44 vfa, vfb;
    kfa.u = *(const uint4*)(Kb + (size_t)(kb + c) * HS + 8 * q);
    vfa.u = *(const uint4*)(Vb + (size_t)((kb >> 2) + q) * 128 + c * 8);
    kfb.u = *(const uint4*)(Kb + (size_t)(kb + 16 + c) * HS + 8 * q);
    vfb.u = *(const uint4*)(Vb + (size_t)(((kb + 16) >> 2) + q) * 128 + c * 8);
    #pragma unroll 4
    for (int i = 0; i < nfast; ++i) {
        int kb2 = kb + 32;   // always < kend + 32 <= qt0 + 32 <= TT: in-batch
        U4H8  kfc; kfc.u = *(const uint4*)(Kb + (size_t)(kb2 + c) * HS + 8 * q);
        U4H44 vfc; vfc.u = *(const uint4*)(Vb + (size_t)((kb2 >> 2) + q) * 128 + c * 8);
        dofast(kfa, vfa);
        kfa = kfb; vfa = vfb; kfb = kfc; vfb = vfc;
        kb += 16;
    }
    if (hasdiag) { domask(kfa, vfa, kb); domask(kfb, vfb, kb + 16); }

    // l: every lane already holds l[c] (ones-A MFMA replicates over rows)
    float lt0 = al0[0];
    float lt1 = al1[0];

    // two 16-query slots: t16 = 2tt (frag0), 2tt+1 (frag1), same sp
    float* P0 = part + (size_t)((b * 256 + 2 * tt) * MAXSP + sp) * SLOT;
    float* P1 = P0 + (size_t)MAXSP * SLOT;
    if (q == 0) { P0[16 + c] = lt0; P1[16 + c] = lt1; }
    // O region: [query c][quad q][4 dwords] — one uint4 store per lane/frag
    H4U4 a;
    a.h[0] = pkf16(o00[0], o00[1]); a.h[1] = pkf16(o00[2], o00[3]);
    a.h[2] = pkf16(o01[0], o01[1]); a.h[3] = pkf16(o01[2], o01[3]);
    *((uint4*)((uint32*)(P0 + 32) + c * 16 + q * 4)) = a.u;
    a.h[0] = pkf16(o10[0], o10[1]); a.h[1] = pkf16(o10[2], o10[3]);
    a.h[2] = pkf16(o11[0], o11[1]); a.h[3] = pkf16(o11[2], o11[3]);
    *((uint4*)((uint32*)(P1 + 32) + c * 16 + q * 4)) = a.u;
}

// ---------------------------------------------------------------------------
// Kernel 3: combine splits (plain sums — shared fixed bias), normalize,
// write fp32 out. One thread per (b, 16q tile, query, quad): 65536 threads.
// ---------------------------------------------------------------------------
__global__ __launch_bounds__(256) void attn_combine(
    const float* __restrict__ part, float* __restrict__ out)
{
    int tid = blockIdx.x * 256 + threadIdx.x;  // 0..65535
    int hq = tid & 3;            // quad block: dims {4hq..4hq+3, 16+4hq..+3}
    int c  = (tid >> 2) & 15;
    int t  = (tid >> 6) & 255;
    int b  = tid >> 14;
    int ns = (t >> 5) + 1;       // 512-key splits covering this 16q tile

    const float* base = part + (size_t)(b * 256 + t) * MAXSP * SLOT;

    float acc[8];
    #pragma unroll
    for (int k = 0; k < 8; ++k) acc[k] = 0.f;
    float L = 0.f;
    for (int s = 0; s < ns; ++s) {
        const float* P = base + (size_t)s * SLOT;
        L += P[16 + c];
        uint4 ov = *(const uint4*)((const uint32*)(P + 32) + c * 16 + 4 * hq);
        const uint32* ovp = (const uint32*)&ov;
        #pragma unroll
        for (int pr = 0; pr < 4; ++pr) {
            half2v hh = u2h(ovp[pr]);
            acc[2 * pr]     += (float)hh.x;
            acc[2 * pr + 1] += (float)hh.y;
        }
    }
    float invL = 1.0f / L;
    float* orow = out + ((size_t)(b * TT + t * 16 + c)) * HS;
    float4 w0 = {acc[0] * invL, acc[1] * invL, acc[2] * invL, acc[3] * invL};
    float4 w1 = {acc[4] * invL, acc[5] * invL, acc[6] * invL, acc[7] * invL};
    *(float4*)(orow + 4 * hq) = w0;        // dims 4hq..4hq+3
    *(float4*)(orow + 16 + 4 * hq) = w1;   // dims 16+4hq..16+4hq+3
}

// ---------------------------------------------------------------------------
extern "C" void kernel_launch(void* const* d_in, const int* in_sizes, int n_in,
                              void* d_out, int out_size, void* d_ws, size_t ws_size,
                              hipStream_t stream)
{
    const float* x  = (const float*)d_in[0];
    const float* Wq = (const float*)d_in[1];
    const float* Wk = (const float*)d_in[2];
    const float* Wv = (const float*)d_in[3];
    float* out = (float*)d_out;

    __fp16* Qh  = (__fp16*)d_ws;                        // 1 MB
    __fp16* Kh  = Qh + (size_t)BB * TT * HS;            // 1 MB
    __fp16* Vt8 = Kh + (size_t)BB * TT * HS;            // 1 MB
    float* part = (float*)(Vt8 + (size_t)BB * TT * HS); // 8192 slots * 1152 B

    qkv_proj<<<dim3((BB * TT * HS) / 256), dim3(256), 0, stream>>>(
        x, Wq, Wk, Wv, Qh, Kh, Vt8);
    attn_partial<<<dim3((BB * IPB) / 4), dim3(256), 0, stream>>>(
        Qh, Kh, Vt8, part);
    attn_combine<<<dim3(256), dim3(256), 0, stream>>>(part, out);
}

// Round 13
// 105.787 us; speedup vs baseline: 1.3757x; 1.0014x over previous
//
#include <hip/hip_runtime.h>
#include <cmath>

// Problem constants (Head: B=4, T=4096, N_EMBD=32, HEAD_SIZE=32)
#define BB 4
#define TT 4096
#define NE 32
#define HS 32

// R9 geometry kept: 512-key splits. R13: ONE WAVE PER BLOCK (64 threads);
// 2304 blocks = exactly 9 per CU — kills the 2.25-blocks/CU 3-round tail
// (22 us = 3 x 7.3 us rounds; 192 CUs idle in round 3).
#define IPB 576       // items per batch = sum_{tt=0}^{127} ceil((tt+1)/16)
#define MAXSP 8       // 512-key splits per 16-query slot (combiner view)
#define SLOT 288      // dwords per slot: [16 unused], l[16], O[16q][4 quad][4 dw]
#define FNEG (-1.0e30f)
#define BIAS 6.0f     // fixed softmax exponent bias (folded into QK mfma C)
#define SC2  0.25506953149031156f  // 32^-0.5 * log2(e), folded into Qh

typedef unsigned int uint32;
typedef __fp16 half2v __attribute__((ext_vector_type(2)));
typedef __fp16 half4v __attribute__((ext_vector_type(4)));
typedef __fp16 half8v __attribute__((ext_vector_type(8)));
typedef float f32x4 __attribute__((ext_vector_type(4)));

__device__ __forceinline__ half2v u2h(uint32 u) {
    union { uint32 u; half2v h; } x; x.u = u; return x.h;
}

#if __has_builtin(__builtin_amdgcn_cvt_pkrtz)
__device__ __forceinline__ half2v pkf16(float a, float b) {
    return __builtin_amdgcn_cvt_pkrtz(a, b);
}
#else
__device__ __forceinline__ half2v pkf16(float a, float b) {
    half2v h; h.x = (__fp16)a; h.y = (__fp16)b; return h;
}
#endif

// ---------------------------------------------------------------------------
// Kernel 1: Q/K/V projection (fp32 math), f16 stores. R7 WIN kept: LDS-
// transposed weight staging (coalesced global reads, conflict-free LDS).
// ---------------------------------------------------------------------------
__global__ __launch_bounds__(256) void qkv_proj(
    const float* __restrict__ x,
    const float* __restrict__ Wq,
    const float* __restrict__ Wk,
    const float* __restrict__ Wv,
    __fp16* __restrict__ Qh, __fp16* __restrict__ Kh,
    __fp16* __restrict__ Vt8)
{
    __shared__ float Wt[3][NE][HS];   // Wt[m][d][h] = Wm[h*NE+d], 12 KB
    #pragma unroll
    for (int i = threadIdx.x; i < 3 * NE * HS; i += 256) {
        int m   = i >> 10;            // matrix 0..2
        int idx = i & 1023;           // contiguous within matrix
        int h   = idx >> 5;           // W row
        int d   = idx & 31;           // W col (contiguous across threads)
        const float* Wm = (m == 0) ? Wq : (m == 1) ? Wk : Wv;
        Wt[m][d][h] = Wm[h * NE + d];
    }
    __syncthreads();

    int tid = blockIdx.x * 256 + threadIdx.x;
    int row = tid >> 5;      // 0..16383  (b*T + t)
    int h   = tid & 31;
    const float4* xr4 = reinterpret_cast<const float4*>(x + (size_t)row * NE);
    float4 xv4[8];
    #pragma unroll
    for (int k = 0; k < 8; ++k) xv4[k] = xr4[k];
    const float* xv = (const float*)xv4;
    float aq = 0.f, ak = 0.f, av = 0.f;
    #pragma unroll
    for (int d = 0; d < NE; ++d) {
        aq = fmaf(xv[d], Wt[0][d][h], aq);
        ak = fmaf(xv[d], Wt[1][d][h], ak);
        av = fmaf(xv[d], Wt[2][d][h], av);
    }
    size_t o = (size_t)row * HS + h;
    Qh[o] = (__fp16)(aq * SC2);
    Kh[o] = (__fp16)ak;
    int b = row >> 12, t = row & (TT - 1);
    Vt8[((size_t)(b * (TT / 4) + (t >> 2)) * 16 + (h & 15)) * 8
        + (h >> 4) * 4 + (t & 3)] = (__fp16)av;
}

// ---------------------------------------------------------------------------
// Kernel 2: MFMA flash partials, 32-query tiles, 512-KEY SPLITS (R12 body).
// R13: 64-thread blocks, item = blockIdx.x. 2304 blocks = 9/CU exactly.
// ---------------------------------------------------------------------------
__global__ __launch_bounds__(64, 4) void attn_partial(
    const __fp16* __restrict__ Qh, const __fp16* __restrict__ Kh,
    const __fp16* __restrict__ Vt8, float* __restrict__ part)
{
    int lane = threadIdx.x & 63;
    int item = (BB * IPB - 1) - blockIdx.x;   // LPT: heavy first
    int b = item / IPB;
    int r = item - b * IPB;
    // group g: prefix = 8g(g+1); solve 8g(g+1) <= r < 8(g+1)(g+2)
    int g = (int)((sqrtf((float)(4 + 2 * r)) - 2.0f) * 0.25f);
    if (g < 0) g = 0;
    while (8 * (g + 1) * (g + 2) <= r) ++g;
    while (8 * g * (g + 1) > r) --g;
    int rr = r - 8 * g * (g + 1);
    int tq = rr / (g + 1);           // 0..15
    int tt = 16 * g + tq;            // 32-query tile index, 0..127
    int sp = rr - tq * (g + 1);      // split index, 0..g
    int qt0 = tt * 32;
    int kbase = sp * 512;
    int kend  = min(kbase + 512, qt0 + 32);
    int nsub  = (kend - kbase) >> 4;      // even: 2..32
    bool hasdiag = (kend == qt0 + 32);    // true iff last split
    int nfast = nsub - (hasdiag ? 2 : 0);

    int c = lane & 15;   // query column (within each 16q fragment)
    int q = lane >> 4;   // quad

    const __fp16* Qb = Qh  + (size_t)b * TT * HS;
    const __fp16* Kb = Kh  + (size_t)b * TT * HS;
    const __fp16* Vb = Vt8 + (size_t)b * (TT / 4) * 128;

    union U4H8  { uint4 u; half8v h; };
    union U4H44 { uint4 u; half4v h4[2]; };
    union H4    { half4v h4; half2v h2[2]; };
    union H4U4  { half2v h[4]; uint4 u; };

    U4H8 qf0; qf0.u = *(const uint4*)(Qb + (size_t)(qt0 + c) * HS + 8 * q);
    U4H8 qf1; qf1.u = *(const uint4*)(Qb + (size_t)(qt0 + 16 + c) * HS + 8 * q);

    const f32x4 cbias = {-BIAS, -BIAS, -BIAS, -BIAS};
    const half4v vones = {(__fp16)1.0f, (__fp16)1.0f, (__fp16)1.0f, (__fp16)1.0f};
    f32x4 o00 = {0.f,0.f,0.f,0.f}, o01 = o00, o10 = o00, o11 = o00;
    f32x4 al0 = o00, al1 = o00;      // l accumulators (ones-A MFMA)

    // ---- one 16-key subtile from preloaded fragments, no causal mask ----
    auto dofast = [&](U4H8 kf, U4H44 vf) {
        f32x4 s0 = __builtin_amdgcn_mfma_f32_16x16x32_f16(kf.h, qf0.h, cbias, 0, 0, 0);
        f32x4 s1 = __builtin_amdgcn_mfma_f32_16x16x32_f16(kf.h, qf1.h, cbias, 0, 0, 0);
        float p0[4], p1[4];
        #pragma unroll
        for (int j = 0; j < 4; ++j) {
            p0[j] = exp2f((s0[j] != -BIAS) ? s0[j] : FNEG);   // tril==0 quirk
            p1[j] = exp2f((s1[j] != -BIAS) ? s1[j] : FNEG);
        }
        H4 pf0; pf0.h2[0] = pkf16(p0[0], p0[1]); pf0.h2[1] = pkf16(p0[2], p0[3]);
        H4 pf1; pf1.h2[0] = pkf16(p1[0], p1[1]); pf1.h2[1] = pkf16(p1[2], p1[3]);
        al0 = __builtin_amdgcn_mfma_f32_16x16x16f16(vones,     pf0.h4, al0, 0, 0, 0);
        al1 = __builtin_amdgcn_mfma_f32_16x16x16f16(vones,     pf1.h4, al1, 0, 0, 0);
        o00 = __builtin_amdgcn_mfma_f32_16x16x16f16(vf.h4[0], pf0.h4, o00, 0, 0, 0);
        o01 = __builtin_amdgcn_mfma_f32_16x16x16f16(vf.h4[1], pf0.h4, o01, 0, 0, 0);
        o10 = __builtin_amdgcn_mfma_f32_16x16x16f16(vf.h4[0], pf1.h4, o10, 0, 0, 0);
        o11 = __builtin_amdgcn_mfma_f32_16x16x16f16(vf.h4[1], pf1.h4, o11, 0, 0, 0);
    };

    // ---- diagonal subtile (preloaded fragments): adds causal masks ----
    auto domask = [&](U4H8 kf, U4H44 vf, int kb) {
        f32x4 s0 = __builtin_amdgcn_mfma_f32_16x16x32_f16(kf.h, qf0.h, cbias, 0, 0, 0);
        f32x4 s1 = __builtin_amdgcn_mfma_f32_16x16x32_f16(kf.h, qf1.h, cbias, 0, 0, 0);
        int r0 = kb - qt0 + 4 * q;        // key offset rel. frag0 queries
        int r1 = r0 - 16;                 // rel. frag1 queries
        float p0[4], p1[4];
        #pragma unroll
        for (int j = 0; j < 4; ++j) {
            float w0 = (s0[j] != -BIAS) ? s0[j] : FNEG;
            float w1 = (s1[j] != -BIAS) ? s1[j] : FNEG;
            if (r0 + j > c) w0 = FNEG;    // causal (frag0)
            if (r1 + j > c) w1 = FNEG;    // causal (frag1)
            p0[j] = exp2f(w0);
            p1[j] = exp2f(w1);
        }
        H4 pf0; pf0.h2[0] = pkf16(p0[0], p0[1]); pf0.h2[1] = pkf16(p0[2], p0[3]);
        H4 pf1; pf1.h2[0] = pkf16(p1[0], p1[1]); pf1.h2[1] = pkf16(p1[2], p1[3]);
        al0 = __builtin_amdgcn_mfma_f32_16x16x16f16(vones,     pf0.h4, al0, 0, 0, 0);
        al1 = __builtin_amdgcn_mfma_f32_16x16x16f16(vones,     pf1.h4, al1, 0, 0, 0);
        o00 = __builtin_amdgcn_mfma_f32_16x16x16f16(vf.h4[0], pf0.h4, o00, 0, 0, 0);
        o01 = __builtin_amdgcn_mfma_f32_16x16x16f16(vf.h4[1], pf0.h4, o01, 0, 0, 0);
        o10 = __builtin_amdgcn_mfma_f32_16x16x16f16(vf.h4[0], pf1.h4, o10, 0, 0, 0);
        o11 = __builtin_amdgcn_mfma_f32_16x16x16f16(vf.h4[1], pf1.h4, o11, 0, 0, 0);
    };

    // ---- 2-deep software-pipelined fast loop ----
    int kb = kbase;
    U4H8  kfa, kfb; U4H44 vfa, vfb;
    kfa.u = *(const uint4*)(Kb + (size_t)(kb + c) * HS + 8 * q);
    vfa.u = *(const uint4*)(Vb + (size_t)((kb >> 2) + q) * 128 + c * 8);
    kfb.u = *(const uint4*)(Kb + (size_t)(kb + 16 + c) * HS + 8 * q);
    vfb.u = *(const uint4*)(Vb + (size_t)(((kb + 16) >> 2) + q) * 128 + c * 8);
    #pragma unroll 4
    for (int i = 0; i < nfast; ++i) {
        int kb2 = kb + 32;   // always < kend + 32 <= qt0 + 32 <= TT: in-batch
        U4H8  kfc; kfc.u = *(const uint4*)(Kb + (size_t)(kb2 + c) * HS + 8 * q);
        U4H44 vfc; vfc.u = *(const uint4*)(Vb + (size_t)((kb2 >> 2) + q) * 128 + c * 8);
        dofast(kfa, vfa);
        kfa = kfb; vfa = vfb; kfb = kfc; vfb = vfc;
        kb += 16;
    }
    if (hasdiag) { domask(kfa, vfa, kb); domask(kfb, vfb, kb + 16); }

    // l: every lane already holds l[c] (ones-A MFMA replicates over rows)
    float lt0 = al0[0];
    float lt1 = al1[0];

    // two 16-query slots: t16 = 2tt (frag0), 2tt+1 (frag1), same sp
    float* P0 = part + (size_t)((b * 256 + 2 * tt) * MAXSP + sp) * SLOT;
    float* P1 = P0 + (size_t)MAXSP * SLOT;
    if (q == 0) { P0[16 + c] = lt0; P1[16 + c] = lt1; }
    // O region: [query c][quad q][4 dwords] — one uint4 store per lane/frag
    H4U4 a;
    a.h[0] = pkf16(o00[0], o00[1]); a.h[1] = pkf16(o00[2], o00[3]);
    a.h[2] = pkf16(o01[0], o01[1]); a.h[3] = pkf16(o01[2], o01[3]);
    *((uint4*)((uint32*)(P0 + 32) + c * 16 + q * 4)) = a.u;
    a.h[0] = pkf16(o10[0], o10[1]); a.h[1] = pkf16(o10[2], o10[3]);
    a.h[2] = pkf16(o11[0], o11[1]); a.h[3] = pkf16(o11[2], o11[3]);
    *((uint4*)((uint32*)(P1 + 32) + c * 16 + q * 4)) = a.u;
}

// ---------------------------------------------------------------------------
// Kernel 3: combine splits (plain sums — shared fixed bias), normalize,
// write fp32 out. One thread per (b, 16q tile, query, quad): 65536 threads.
// ---------------------------------------------------------------------------
__global__ __launch_bounds__(256) void attn_combine(
    const float* __restrict__ part, float* __restrict__ out)
{
    int tid = blockIdx.x * 256 + threadIdx.x;  // 0..65535
    int hq = tid & 3;            // quad block: dims {4hq..4hq+3, 16+4hq..+3}
    int c  = (tid >> 2) & 15;
    int t  = (tid >> 6) & 255;
    int b  = tid >> 14;
    int ns = (t >> 5) + 1;       // 512-key splits covering this 16q tile

    const float* base = part + (size_t)(b * 256 + t) * MAXSP * SLOT;

    float acc[8];
    #pragma unroll
    for (int k = 0; k < 8; ++k) acc[k] = 0.f;
    float L = 0.f;
    for (int s = 0; s < ns; ++s) {
        const float* P = base + (size_t)s * SLOT;
        L += P[16 + c];
        uint4 ov = *(const uint4*)((const uint32*)(P + 32) + c * 16 + 4 * hq);
        const uint32* ovp = (const uint32*)&ov;
        #pragma unroll
        for (int pr = 0; pr < 4; ++pr) {
            half2v hh = u2h(ovp[pr]);
            acc[2 * pr]     += (float)hh.x;
            acc[2 * pr + 1] += (float)hh.y;
        }
    }
    float invL = 1.0f / L;
    float* orow = out + ((size_t)(b * TT + t * 16 + c)) * HS;
    float4 w0 = {acc[0] * invL, acc[1] * invL, acc[2] * invL, acc[3] * invL};
    float4 w1 = {acc[4] * invL, acc[5] * invL, acc[6] * invL, acc[7] * invL};
    *(float4*)(orow + 4 * hq) = w0;        // dims 4hq..4hq+3
    *(float4*)(orow + 16 + 4 * hq) = w1;   // dims 16+4hq..16+4hq+3
}

// ---------------------------------------------------------------------------
extern "C" void kernel_launch(void* const* d_in, const int* in_sizes, int n_in,
                              void* d_out, int out_size, void* d_ws, size_t ws_size,
                              hipStream_t stream)
{
    const float* x  = (const float*)d_in[0];
    const float* Wq = (const float*)d_in[1];
    const float* Wk = (const float*)d_in[2];
    const float* Wv = (const float*)d_in[3];
    float* out = (float*)d_out;

    __fp16* Qh  = (__fp16*)d_ws;                        // 1 MB
    __fp16* Kh  = Qh + (size_t)BB * TT * HS;            // 1 MB
    __fp16* Vt8 = Kh + (size_t)BB * TT * HS;            // 1 MB
    float* part = (float*)(Vt8 + (size_t)BB * TT * HS); // 8192 slots * 1152 B

    qkv_proj<<<dim3((BB * TT * HS) / 256), dim3(256), 0, stream>>>(
        x, Wq, Wk, Wv, Qh, Kh, Vt8);
    // R13: one wave per block — 2304 blocks = exactly 9 per CU (no tail round)
    attn_partial<<<dim3(BB * IPB), dim3(64), 0, stream>>>(
        Qh, Kh, Vt8, part);
    attn_combine<<<dim3(256), dim3(256), 0, stream>>>(part, out);
}

// Round 14
// 103.556 us; speedup vs baseline: 1.4053x; 1.0215x over previous
//
#include <hip/hip_runtime.h>
#include <cmath>

// Problem constants (Head: B=4, T=4096, N_EMBD=32, HEAD_SIZE=32)
#define BB 4
#define TT 4096
#define NE 32
#define HS 32

// R9 geometry kept: 512-key splits; R13 1-wave blocks kept (neutral).
// R14: per-wave 2-STREAM INTERLEAVE — even/odd subtiles in independent
// accumulator sets; halves the serial chain of the heaviest (32-subtile)
// wave, whose span == kernel duration (22us/32 = ~1650cy/subtile).
#define IPB 576       // items per batch = sum_{tt=0}^{127} ceil((tt+1)/16)
#define MAXSP 8       // 512-key splits per 16-query slot (combiner view)
#define SLOT 288      // dwords per slot: [16 unused], l[16], O[16q][4 quad][4 dw]
#define FNEG (-1.0e30f)
#define BIAS 6.0f     // fixed softmax exponent bias (folded into QK mfma C)
#define SC2  0.25506953149031156f  // 32^-0.5 * log2(e), folded into Qh

typedef unsigned int uint32;
typedef __fp16 half2v __attribute__((ext_vector_type(2)));
typedef __fp16 half4v __attribute__((ext_vector_type(4)));
typedef __fp16 half8v __attribute__((ext_vector_type(8)));
typedef float f32x4 __attribute__((ext_vector_type(4)));

__device__ __forceinline__ half2v u2h(uint32 u) {
    union { uint32 u; half2v h; } x; x.u = u; return x.h;
}

#if __has_builtin(__builtin_amdgcn_cvt_pkrtz)
__device__ __forceinline__ half2v pkf16(float a, float b) {
    return __builtin_amdgcn_cvt_pkrtz(a, b);
}
#else
__device__ __forceinline__ half2v pkf16(float a, float b) {
    half2v h; h.x = (__fp16)a; h.y = (__fp16)b; return h;
}
#endif

// ---------------------------------------------------------------------------
// Kernel 1: Q/K/V projection (fp32 math), f16 stores. R7 WIN kept: LDS-
// transposed weight staging (coalesced global reads, conflict-free LDS).
// ---------------------------------------------------------------------------
__global__ __launch_bounds__(256) void qkv_proj(
    const float* __restrict__ x,
    const float* __restrict__ Wq,
    const float* __restrict__ Wk,
    const float* __restrict__ Wv,
    __fp16* __restrict__ Qh, __fp16* __restrict__ Kh,
    __fp16* __restrict__ Vt8)
{
    __shared__ float Wt[3][NE][HS];   // Wt[m][d][h] = Wm[h*NE+d], 12 KB
    #pragma unroll
    for (int i = threadIdx.x; i < 3 * NE * HS; i += 256) {
        int m   = i >> 10;            // matrix 0..2
        int idx = i & 1023;           // contiguous within matrix
        int h   = idx >> 5;           // W row
        int d   = idx & 31;           // W col (contiguous across threads)
        const float* Wm = (m == 0) ? Wq : (m == 1) ? Wk : Wv;
        Wt[m][d][h] = Wm[h * NE + d];
    }
    __syncthreads();

    int tid = blockIdx.x * 256 + threadIdx.x;
    int row = tid >> 5;      // 0..16383  (b*T + t)
    int h   = tid & 31;
    const float4* xr4 = reinterpret_cast<const float4*>(x + (size_t)row * NE);
    float4 xv4[8];
    #pragma unroll
    for (int k = 0; k < 8; ++k) xv4[k] = xr4[k];
    const float* xv = (const float*)xv4;
    float aq = 0.f, ak = 0.f, av = 0.f;
    #pragma unroll
    for (int d = 0; d < NE; ++d) {
        aq = fmaf(xv[d], Wt[0][d][h], aq);
        ak = fmaf(xv[d], Wt[1][d][h], ak);
        av = fmaf(xv[d], Wt[2][d][h], av);
    }
    size_t o = (size_t)row * HS + h;
    Qh[o] = (__fp16)(aq * SC2);
    Kh[o] = (__fp16)ak;
    int b = row >> 12, t = row & (TT - 1);
    Vt8[((size_t)(b * (TT / 4) + (t >> 2)) * 16 + (h & 15)) * 8
        + (h >> 4) * 4 + (t & 3)] = (__fp16)av;
}

// ---------------------------------------------------------------------------
// Kernel 2: MFMA flash partials, 32-query tiles, 512-KEY SPLITS.
// R14: even/odd subtiles processed as two independent streams (A/B) with
// separate accumulators, merged after the loop — ILP-2 through the whole
// QK->exp2->cvt->PV dependency chain, halving the per-wave critical path.
// ---------------------------------------------------------------------------
__global__ __launch_bounds__(64, 4) void attn_partial(
    const __fp16* __restrict__ Qh, const __fp16* __restrict__ Kh,
    const __fp16* __restrict__ Vt8, float* __restrict__ part)
{
    int lane = threadIdx.x & 63;
    int item = (BB * IPB - 1) - blockIdx.x;   // LPT: heavy first
    int b = item / IPB;
    int r = item - b * IPB;
    // group g: prefix = 8g(g+1); solve 8g(g+1) <= r < 8(g+1)(g+2)
    int g = (int)((sqrtf((float)(4 + 2 * r)) - 2.0f) * 0.25f);
    if (g < 0) g = 0;
    while (8 * (g + 1) * (g + 2) <= r) ++g;
    while (8 * g * (g + 1) > r) --g;
    int rr = r - 8 * g * (g + 1);
    int tq = rr / (g + 1);           // 0..15
    int tt = 16 * g + tq;            // 32-query tile index, 0..127
    int sp = rr - tq * (g + 1);      // split index, 0..g
    int qt0 = tt * 32;
    int kbase = sp * 512;
    int kend  = min(kbase + 512, qt0 + 32);
    int nsub  = (kend - kbase) >> 4;      // even: 2..32
    bool hasdiag = (kend == qt0 + 32);    // true iff last split
    int nfast = nsub - (hasdiag ? 2 : 0); // even (incl. 0)
    int nh = nfast >> 1;                  // iterations of the paired loop

    int c = lane & 15;   // query column (within each 16q fragment)
    int q = lane >> 4;   // quad

    const __fp16* Qb = Qh  + (size_t)b * TT * HS;
    const __fp16* Kb = Kh  + (size_t)b * TT * HS;
    const __fp16* Vb = Vt8 + (size_t)b * (TT / 4) * 128;

    union U4H8  { uint4 u; half8v h; };
    union U4H44 { uint4 u; half4v h4[2]; };
    union H4    { half4v h4; half2v h2[2]; };
    union H4U4  { half2v h[4]; uint4 u; };

    U4H8 qf0; qf0.u = *(const uint4*)(Qb + (size_t)(qt0 + c) * HS + 8 * q);
    U4H8 qf1; qf1.u = *(const uint4*)(Qb + (size_t)(qt0 + 16 + c) * HS + 8 * q);

    const f32x4 cbias = {-BIAS, -BIAS, -BIAS, -BIAS};
    const half4v vones = {(__fp16)1.0f, (__fp16)1.0f, (__fp16)1.0f, (__fp16)1.0f};
    const f32x4 z = {0.f, 0.f, 0.f, 0.f};
    // Stream A accumulators (also receive the diagonal subtiles)
    f32x4 oA00 = z, oA01 = z, oA10 = z, oA11 = z, alA0 = z, alA1 = z;
    // Stream B accumulators
    f32x4 oB00 = z, oB01 = z, oB10 = z, oB11 = z, alB0 = z, alB1 = z;

    // ---- one 16-key subtile into caller-chosen accumulators, no mask ----
    auto dotile = [&](U4H8 kf, U4H44 vf, f32x4& x00, f32x4& x01,
                      f32x4& x10, f32x4& x11, f32x4& a0, f32x4& a1) {
        f32x4 s0 = __builtin_amdgcn_mfma_f32_16x16x32_f16(kf.h, qf0.h, cbias, 0, 0, 0);
        f32x4 s1 = __builtin_amdgcn_mfma_f32_16x16x32_f16(kf.h, qf1.h, cbias, 0, 0, 0);
        float p0[4], p1[4];
        #pragma unroll
        for (int j = 0; j < 4; ++j) {
            p0[j] = exp2f((s0[j] != -BIAS) ? s0[j] : FNEG);   // tril==0 quirk
            p1[j] = exp2f((s1[j] != -BIAS) ? s1[j] : FNEG);
        }
        H4 pf0; pf0.h2[0] = pkf16(p0[0], p0[1]); pf0.h2[1] = pkf16(p0[2], p0[3]);
        H4 pf1; pf1.h2[0] = pkf16(p1[0], p1[1]); pf1.h2[1] = pkf16(p1[2], p1[3]);
        a0  = __builtin_amdgcn_mfma_f32_16x16x16f16(vones,     pf0.h4, a0, 0, 0, 0);
        a1  = __builtin_amdgcn_mfma_f32_16x16x16f16(vones,     pf1.h4, a1, 0, 0, 0);
        x00 = __builtin_amdgcn_mfma_f32_16x16x16f16(vf.h4[0], pf0.h4, x00, 0, 0, 0);
        x01 = __builtin_amdgcn_mfma_f32_16x16x16f16(vf.h4[1], pf0.h4, x01, 0, 0, 0);
        x10 = __builtin_amdgcn_mfma_f32_16x16x16f16(vf.h4[0], pf1.h4, x10, 0, 0, 0);
        x11 = __builtin_amdgcn_mfma_f32_16x16x16f16(vf.h4[1], pf1.h4, x11, 0, 0, 0);
    };

    // ---- diagonal subtile (own loads): adds causal masks, accs into A ----
    auto domask = [&](int kb) {
        U4H8 kf; kf.u = *(const uint4*)(Kb + (size_t)(kb + c) * HS + 8 * q);
        U4H44 vf; vf.u = *(const uint4*)(Vb + (size_t)((kb >> 2) + q) * 128 + c * 8);
        f32x4 s0 = __builtin_amdgcn_mfma_f32_16x16x32_f16(kf.h, qf0.h, cbias, 0, 0, 0);
        f32x4 s1 = __builtin_amdgcn_mfma_f32_16x16x32_f16(kf.h, qf1.h, cbias, 0, 0, 0);
        int r0 = kb - qt0 + 4 * q;        // key offset rel. frag0 queries
        int r1 = r0 - 16;                 // rel. frag1 queries
        float p0[4], p1[4];
        #pragma unroll
        for (int j = 0; j < 4; ++j) {
            float w0 = (s0[j] != -BIAS) ? s0[j] : FNEG;
            float w1 = (s1[j] != -BIAS) ? s1[j] : FNEG;
            if (r0 + j > c) w0 = FNEG;    // causal (frag0)
            if (r1 + j > c) w1 = FNEG;    // causal (frag1)
            p0[j] = exp2f(w0);
            p1[j] = exp2f(w1);
        }
        H4 pf0; pf0.h2[0] = pkf16(p0[0], p0[1]); pf0.h2[1] = pkf16(p0[2], p0[3]);
        H4 pf1; pf1.h2[0] = pkf16(p1[0], p1[1]); pf1.h2[1] = pkf16(p1[2], p1[3]);
        alA0 = __builtin_amdgcn_mfma_f32_16x16x16f16(vones,     pf0.h4, alA0, 0, 0, 0);
        alA1 = __builtin_amdgcn_mfma_f32_16x16x16f16(vones,     pf1.h4, alA1, 0, 0, 0);
        oA00 = __builtin_amdgcn_mfma_f32_16x16x16f16(vf.h4[0], pf0.h4, oA00, 0, 0, 0);
        oA01 = __builtin_amdgcn_mfma_f32_16x16x16f16(vf.h4[1], pf0.h4, oA01, 0, 0, 0);
        oA10 = __builtin_amdgcn_mfma_f32_16x16x16f16(vf.h4[0], pf1.h4, oA10, 0, 0, 0);
        oA11 = __builtin_amdgcn_mfma_f32_16x16x16f16(vf.h4[1], pf1.h4, oA11, 0, 0, 0);
    };

    // ---- paired fast loop: stream A = even subtiles, B = odd subtiles ----
    // Per iteration: prefetch next PAIR, then compute A_i and B_i — fully
    // independent chains (separate accumulators) → ILP-2 end to end.
    int kb = kbase;
    U4H8  kfa, kfb; U4H44 vfa, vfb;
    kfa.u = *(const uint4*)(Kb + (size_t)(kb + c) * HS + 8 * q);
    vfa.u = *(const uint4*)(Vb + (size_t)((kb >> 2) + q) * 128 + c * 8);
    kfb.u = *(const uint4*)(Kb + (size_t)(kb + 16 + c) * HS + 8 * q);
    vfb.u = *(const uint4*)(Vb + (size_t)(((kb + 16) >> 2) + q) * 128 + c * 8);
    #pragma unroll 2
    for (int i = 0; i < nh; ++i) {
        int kb2 = kb + 32;   // next pair; always <= kend <= qt0+32 <= TT
        U4H8  kfc; kfc.u = *(const uint4*)(Kb + (size_t)(kb2 + c) * HS + 8 * q);
        U4H44 vfc; vfc.u = *(const uint4*)(Vb + (size_t)((kb2 >> 2) + q) * 128 + c * 8);
        U4H8  kfd; kfd.u = *(const uint4*)(Kb + (size_t)(kb2 + 16 + c) * HS + 8 * q);
        U4H44 vfd; vfd.u = *(const uint4*)(Vb + (size_t)(((kb2 + 16) >> 2) + q) * 128 + c * 8);
        dotile(kfa, vfa, oA00, oA01, oA10, oA11, alA0, alA1);
        dotile(kfb, vfb, oB00, oB01, oB10, oB11, alB0, alB1);
        kfa = kfc; vfa = vfc; kfb = kfd; vfb = vfd;
        kb = kb2;
    }
    if (hasdiag) { domask(kb); domask(kb + 16); }

    // merge streams
    f32x4 o00 = oA00 + oB00, o01 = oA01 + oB01;
    f32x4 o10 = oA10 + oB10, o11 = oA11 + oB11;
    float lt0 = alA0[0] + alB0[0];
    float lt1 = alA1[0] + alB1[0];

    // two 16-query slots: t16 = 2tt (frag0), 2tt+1 (frag1), same sp
    float* P0 = part + (size_t)((b * 256 + 2 * tt) * MAXSP + sp) * SLOT;
    float* P1 = P0 + (size_t)MAXSP * SLOT;
    if (q == 0) { P0[16 + c] = lt0; P1[16 + c] = lt1; }
    // O region: [query c][quad q][4 dwords] — one uint4 store per lane/frag
    H4U4 a;
    a.h[0] = pkf16(o00[0], o00[1]); a.h[1] = pkf16(o00[2], o00[3]);
    a.h[2] = pkf16(o01[0], o01[1]); a.h[3] = pkf16(o01[2], o01[3]);
    *((uint4*)((uint32*)(P0 + 32) + c * 16 + q * 4)) = a.u;
    a.h[0] = pkf16(o10[0], o10[1]); a.h[1] = pkf16(o10[2], o10[3]);
    a.h[2] = pkf16(o11[0], o11[1]); a.h[3] = pkf16(o11[2], o11[3]);
    *((uint4*)((uint32*)(P1 + 32) + c * 16 + q * 4)) = a.u;
}

// ---------------------------------------------------------------------------
// Kernel 3: combine splits (plain sums — shared fixed bias), normalize,
// write fp32 out. One thread per (b, 16q tile, query, quad): 65536 threads.
// ---------------------------------------------------------------------------
__global__ __launch_bounds__(256) void attn_combine(
    const float* __restrict__ part, float* __restrict__ out)
{
    int tid = blockIdx.x * 256 + threadIdx.x;  // 0..65535
    int hq = tid & 3;            // quad block: dims {4hq..4hq+3, 16+4hq..+3}
    int c  = (tid >> 2) & 15;
    int t  = (tid >> 6) & 255;
    int b  = tid >> 14;
    int ns = (t >> 5) + 1;       // 512-key splits covering this 16q tile

    const float* base = part + (size_t)(b * 256 + t) * MAXSP * SLOT;

    float acc[8];
    #pragma unroll
    for (int k = 0; k < 8; ++k) acc[k] = 0.f;
    float L = 0.f;
    for (int s = 0; s < ns; ++s) {
        const float* P = base + (size_t)s * SLOT;
        L += P[16 + c];
        uint4 ov = *(const uint4*)((const uint32*)(P + 32) + c * 16 + 4 * hq);
        const uint32* ovp = (const uint32*)&ov;
        #pragma unroll
        for (int pr = 0; pr < 4; ++pr) {
            half2v hh = u2h(ovp[pr]);
            acc[2 * pr]     += (float)hh.x;
            acc[2 * pr + 1] += (float)hh.y;
        }
    }
    float invL = 1.0f / L;
    float* orow = out + ((size_t)(b * TT + t * 16 + c)) * HS;
    float4 w0 = {acc[0] * invL, acc[1] * invL, acc[2] * invL, acc[3] * invL};
    float4 w1 = {acc[4] * invL, acc[5] * invL, acc[6] * invL, acc[7] * invL};
    *(float4*)(orow + 4 * hq) = w0;        // dims 4hq..4hq+3
    *(float4*)(orow + 16 + 4 * hq) = w1;   // dims 16+4hq..16+4hq+3
}

// ---------------------------------------------------------------------------
extern "C" void kernel_launch(void* const* d_in, const int* in_sizes, int n_in,
                              void* d_out, int out_size, void* d_ws, size_t ws_size,
                              hipStream_t stream)
{
    const float* x  = (const float*)d_in[0];
    const float* Wq = (const float*)d_in[1];
    const float* Wk = (const float*)d_in[2];
    const float* Wv = (const float*)d_in[3];
    float* out = (float*)d_out;

    __fp16* Qh  = (__fp16*)d_ws;                        // 1 MB
    __fp16* Kh  = Qh + (size_t)BB * TT * HS;            // 1 MB
    __fp16* Vt8 = Kh + (size_t)BB * TT * HS;            // 1 MB
    float* part = (float*)(Vt8 + (size_t)BB * TT * HS); // 8192 slots * 1152 B

    qkv_proj<<<dim3((BB * TT * HS) / 256), dim3(256), 0, stream>>>(
        x, Wq, Wk, Wv, Qh, Kh, Vt8);
    attn_partial<<<dim3(BB * IPB), dim3(64), 0, stream>>>(
        Qh, Kh, Vt8, part);
    attn_combine<<<dim3(256), dim3(256), 0, stream>>>(part, out);
}